// Round 14
// baseline (26.385 us; speedup 1.0000x reference)
//
#include <hip/hip_runtime.h>
#include <hip/hip_bf16.h>

// T=256, B=8, H1=512, U=64, H2=512, V=128
// out[b,t,u,v] = f[t,b,:]·W[:512,v] + g[b,u,:]·W[512:,v] + bias[v]; f_lens tail (8).
// K1 proj5 (160 blocks x 16 rows): P GEMM, SPLIT-N — wave w owns j-cols {2w,2w+1},
//   full K=512. No LDS, no barrier, no reduce; acc -> P direct. B via proven scalar
//   gathers from raw f32 W (same total gather count as split-K, minus all overhead).
// K2 bcast (2048 blocks): R6-verbatim broadcast-store (panel L2-hot, at floor).
// Journal: R4/R5 no in-kernel cross-block sync. R7 no per-step barriers @1blk/CU.
//   R8/R9 ws-bf16-fragment tables -> MFMA: absmax anomalies — abandoned.
//   R10/R12 pf-in-consumer never amortizes. R11 bcast inner loop at floor.
//   R13 16-row tiles beat 8-row (TA amortization): 23.8us.

typedef float  f32x4 __attribute__((ext_vector_type(4)));
typedef short  bh8   __attribute__((ext_vector_type(8)));

__device__ __forceinline__ unsigned short f2bf(float x) {
    unsigned u = __float_as_uint(x);
    return (unsigned short)((u + 0x7FFFu + ((u >> 16) & 1u)) >> 16);
}

__device__ __forceinline__ bh8 cvt8(f32x4 a, f32x4 b) {
    bh8 r;
    r[0] = (short)f2bf(a[0]); r[1] = (short)f2bf(a[1]);
    r[2] = (short)f2bf(a[2]); r[3] = (short)f2bf(a[3]);
    r[4] = (short)f2bf(b[0]); r[5] = (short)f2bf(b[1]);
    r[6] = (short)f2bf(b[2]); r[7] = (short)f2bf(b[3]);
    return r;
}

// ---------------- K1: P GEMM, 160 blocks x 16 rows, split-N, full-K -----------------
// P rows 0..2047: pf (r = b*256+t);  rows 2048..2559: pg (r = 2048+b*64+u).
__global__ __launch_bounds__(256) void proj5(const float* __restrict__ F,
                                             const float* __restrict__ G,
                                             const float* __restrict__ W,
                                             float* __restrict__ P) {
    const int tid = threadIdx.x;
    const int rows16 = blockIdx.x * 16;          // P row base
    const bool isF = rows16 < 2048;
    const int koff = isF ? 0 : 512;
    const int w = tid >> 6, lane = tid & 63, l15 = lane & 15, cc = lane >> 4;

    const int rr = rows16 + l15;                 // A row for this lane
    const float* arow = isF ? F + (((rr & 255) << 3) + (rr >> 8)) * 512   // f[t][b][:]
                            : G + (rr - 2048) * 512;                      // g[b*64+u][:]
    const int c0 = w * 32;                       // wave's 2 j-columns start here

    f32x4 acc[2] = {};
#pragma unroll 4
    for (int kk = 0; kk < 16; ++kk) {
        const int k0 = kk * 32 + cc * 8;         // this lane's 8-k chunk
        f32x4 a0 = *reinterpret_cast<const f32x4*>(arow + k0);
        f32x4 a1 = *reinterpret_cast<const f32x4*>(arow + k0 + 4);
        bh8 av = cvt8(a0, a1);
#pragma unroll
        for (int jj = 0; jj < 2; ++jj) {
            const float* wsrc = W + (koff + k0) * 128 + (c0 + jj * 16 + l15);
            bh8 bv;
#pragma unroll
            for (int i = 0; i < 8; ++i) bv[i] = (short)f2bf(wsrc[i * 128]);
            acc[jj] = __builtin_amdgcn_mfma_f32_16x16x32_bf16(av, bv, acc[jj], 0, 0, 0);
        }
    }

    // D map (proven): col = l15, row m = cc*4+q; wave writes its 2 j-columns
#pragma unroll
    for (int jj = 0; jj < 2; ++jj)
#pragma unroll
        for (int q = 0; q < 4; ++q)
            P[(rows16 + cc * 4 + q) * 128 + c0 + jj * 16 + l15] = acc[jj][q];
}

// ---------------- K2: broadcast add + stream out + lens tail (R6 verbatim) ----------
__global__ __launch_bounds__(256) void bcast(const float* __restrict__ P,
                                             const float* __restrict__ bias,
                                             const int* __restrict__ f_lens,
                                             float* __restrict__ out,
                                             int lens_off) {
    const int r   = blockIdx.x;        // b*256 + t
    const int tid = threadIdx.x;
    const int b   = r >> 8;
    const int vq  = tid & 31;          // float4 index in V
    const int u0  = tid >> 5;          // 0..7

    f32x4 pf = *reinterpret_cast<const f32x4*>(P + r * 128 + vq * 4);
    f32x4 bi = *reinterpret_cast<const f32x4*>(bias + vq * 4);
    pf += bi;

    const float* pg = P + (2048 + b * 64) * 128;
    float* ob = out + (size_t)r * 8192;

#pragma unroll
    for (int i = 0; i < 8; ++i) {
        int u = u0 * 8 + i;
        f32x4 v = *reinterpret_cast<const f32x4*>(pg + u * 128 + vq * 4);
        v += pf;
        *reinterpret_cast<f32x4*>(ob + u * 128 + vq * 4) = v;
    }

    if (r == 0 && tid < 8) out[lens_off + tid] = (float)f_lens[tid];
}

extern "C" void kernel_launch(void* const* d_in, const int* in_sizes, int n_in,
                              void* d_out, int out_size, void* d_ws, size_t ws_size,
                              hipStream_t stream) {
    const float* f      = (const float*)d_in[0];
    const int*   f_lens = (const int*)  d_in[1];
    const float* g      = (const float*)d_in[2];
    // d_in[3] = g_lens (unused by reference output)
    const float* W      = (const float*)d_in[4];
    const float* bias   = (const float*)d_in[5];
    float* out = (float*)d_out;

    float* P = (float*)d_ws;                                   // 2560*128*4 = 1.25 MB

    proj5<<<dim3(160),  dim3(256), 0, stream>>>(f, g, W, P);
    bcast<<<dim3(2048), dim3(256), 0, stream>>>(P, bias, f_lens, out, out_size - 8);
}

// Round 15
// 23.589 us; speedup vs baseline: 1.1185x; 1.1185x over previous
//
#include <hip/hip_runtime.h>
#include <hip/hip_bf16.h>

// T=256, B=8, H1=512, U=64, H2=512, V=128
// out[b,t,u,v] = f[t,b,:]·W[:512,v] + g[b,u,:]·W[512:,v] + bias[v]; f_lens tail (8).
// K1 proj6 (160 blocks x 512 thr = 8 waves x 16 rows): P GEMM, wave-split-K (8x64),
//   B-fragments via proven scalar gathers from raw f32 W; per-wave gathers halved
//   vs R13 (deeper TA overlap), 64 KB sred, 8-way reduce.
// K2 bcast (2048 blocks): R6-verbatim broadcast-store (panel L2-hot, at floor).
// Journal: R4/R5 no in-kernel cross-block sync. R7 no per-step barriers @1blk/CU.
//   R8/R9 ws-bf16-fragment tables -> MFMA: absmax anomalies — abandoned.
//   R10/R12 pf-in-consumer never amortizes. R11 bcast inner loop at floor.
//   R13 split-K 16-row = 23.8us best. R14 split-N regressed (serial MFMA chains).

typedef float  f32x4 __attribute__((ext_vector_type(4)));
typedef short  bh8   __attribute__((ext_vector_type(8)));

__device__ __forceinline__ unsigned short f2bf(float x) {
    unsigned u = __float_as_uint(x);
    return (unsigned short)((u + 0x7FFFu + ((u >> 16) & 1u)) >> 16);
}

__device__ __forceinline__ bh8 cvt8(f32x4 a, f32x4 b) {
    bh8 r;
    r[0] = (short)f2bf(a[0]); r[1] = (short)f2bf(a[1]);
    r[2] = (short)f2bf(a[2]); r[3] = (short)f2bf(a[3]);
    r[4] = (short)f2bf(b[0]); r[5] = (short)f2bf(b[1]);
    r[6] = (short)f2bf(b[2]); r[7] = (short)f2bf(b[3]);
    return r;
}

// ------------- K1: P GEMM, 160 blocks x 16 rows, 8-wave split-K (8x64) --------------
// P rows 0..2047: pf (r = b*256+t);  rows 2048..2559: pg (r = 2048+b*64+u).
__global__ __launch_bounds__(512) void proj6(const float* __restrict__ F,
                                             const float* __restrict__ G,
                                             const float* __restrict__ W,
                                             float* __restrict__ P) {
    __shared__ float sred[8][16][128];           // 64 KB

    const int tid = threadIdx.x;
    const int rows16 = blockIdx.x * 16;          // P row base
    const bool isF = rows16 < 2048;
    const int koff = isF ? 0 : 512;
    const int w = tid >> 6, lane = tid & 63, l15 = lane & 15, cc = lane >> 4;

    const int rr = rows16 + l15;                 // 16 real rows
    const float* arow = isF ? F + (((rr & 255) << 3) + (rr >> 8)) * 512   // f[t][b][:]
                            : G + (rr - 2048) * 512;                      // g[b*64+u][:]

    f32x4 acc[8] = {};
#pragma unroll
    for (int kk = 0; kk < 2; ++kk) {
        const int k0 = w * 64 + kk * 32 + cc * 8;
        f32x4 a0 = *reinterpret_cast<const f32x4*>(arow + k0);
        f32x4 a1 = *reinterpret_cast<const f32x4*>(arow + k0 + 4);
        bh8 av = cvt8(a0, a1);
#pragma unroll
        for (int j = 0; j < 8; ++j) {
            const float* wsrc = W + (koff + k0) * 128 + (j * 16 + l15);
            bh8 bv;
#pragma unroll
            for (int i = 0; i < 8; ++i) bv[i] = (short)f2bf(wsrc[i * 128]);
            acc[j] = __builtin_amdgcn_mfma_f32_16x16x32_bf16(av, bv, acc[j], 0, 0, 0);
        }
    }
    // D rows m = cc*4+q in [0,16), all real
#pragma unroll
    for (int j = 0; j < 8; ++j)
#pragma unroll
        for (int q = 0; q < 4; ++q)
            sred[w][cc * 4 + q][j * 16 + l15] = acc[j][q];
    __syncthreads();

    // reduce 8 waves, write 16 rows: thread -> (row = tid>>5, f32x4 chunk = tid&31)
    const int row = tid >> 5, colq = tid & 31;
    f32x4 s = {};
#pragma unroll
    for (int ww = 0; ww < 8; ++ww)
        s += *reinterpret_cast<const f32x4*>(&sred[ww][row][colq * 4]);
    *reinterpret_cast<f32x4*>(P + (rows16 + row) * 128 + colq * 4) = s;
}

// ---------------- K2: broadcast add + stream out + lens tail (R6 verbatim) ----------
__global__ __launch_bounds__(256) void bcast(const float* __restrict__ P,
                                             const float* __restrict__ bias,
                                             const int* __restrict__ f_lens,
                                             float* __restrict__ out,
                                             int lens_off) {
    const int r   = blockIdx.x;        // b*256 + t
    const int tid = threadIdx.x;
    const int b   = r >> 8;
    const int vq  = tid & 31;          // float4 index in V
    const int u0  = tid >> 5;          // 0..7

    f32x4 pf = *reinterpret_cast<const f32x4*>(P + r * 128 + vq * 4);
    f32x4 bi = *reinterpret_cast<const f32x4*>(bias + vq * 4);
    pf += bi;

    const float* pg = P + (2048 + b * 64) * 128;
    float* ob = out + (size_t)r * 8192;

#pragma unroll
    for (int i = 0; i < 8; ++i) {
        int u = u0 * 8 + i;
        f32x4 v = *reinterpret_cast<const f32x4*>(pg + u * 128 + vq * 4);
        v += pf;
        *reinterpret_cast<f32x4*>(ob + u * 128 + vq * 4) = v;
    }

    if (r == 0 && tid < 8) out[lens_off + tid] = (float)f_lens[tid];
}

extern "C" void kernel_launch(void* const* d_in, const int* in_sizes, int n_in,
                              void* d_out, int out_size, void* d_ws, size_t ws_size,
                              hipStream_t stream) {
    const float* f      = (const float*)d_in[0];
    const int*   f_lens = (const int*)  d_in[1];
    const float* g      = (const float*)d_in[2];
    // d_in[3] = g_lens (unused by reference output)
    const float* W      = (const float*)d_in[4];
    const float* bias   = (const float*)d_in[5];
    float* out = (float*)d_out;

    float* P = (float*)d_ws;                                   // 2560*128*4 = 1.25 MB

    proj6<<<dim3(160),  dim3(512), 0, stream>>>(f, g, W, P);
    bcast<<<dim3(2048), dim3(256), 0, stream>>>(P, bias, f_lens, out, out_size - 8);
}